// Round 2
// baseline (319.606 us; speedup 1.0000x reference)
//
#include <hip/hip_runtime.h>

#define TWOPI_256 0.024543692606170259f  // 2*pi/256

typedef __attribute__((ext_vector_type(8))) short bf16x8;
typedef __attribute__((ext_vector_type(4))) float f32x4;

__device__ __forceinline__ unsigned int bfp(float a) {
  return (__float_as_uint(a) + 0x8000u) >> 16;
}
__device__ __forceinline__ float bf2f(unsigned int h) {
  return __uint_as_float(h << 16);
}

// ---------------- Kernel 1: per (b,ci) image -> 32x16 spectral modes ----------------
// Stage A (MFMA): P[h][k] = sum_w x[h][w] e^{-2pi i k w/256}, as X[256x256]*E[256x16]
//   x and E split hi/lo bf16, 3-term mfma => ~fp32 accuracy.
// Stage B (VALU, unchanged): Xm[t][k] = sum_h P[h][k] e^{-2pi i ky_t h/256}
__global__ __launch_bounds__(256) void k1_fwd(const float* __restrict__ x,
                                              float2* __restrict__ Xm) {
  const int blk = blockIdx.x;  // b*64 + ci
  const int tid = threadIdx.x;
  const int lane = tid & 63;
  const int wv = tid >> 6;   // wave id 0..3
  const int llo = lane & 15;
  const int lhi = lane >> 4;

  __shared__ float tabc[256];
  __shared__ float tabs[256];
  // E tables, B-operand layout [kk][w] (row stride 264 shorts = 528B, 16B aligned)
  __shared__ short EbRH[16][264];
  __shared__ short EbRL[16][264];
  __shared__ short EbIH[16][264];
  __shared__ short EbIL[16][264];
  // X chunk (32 rows), A-operand layout [row][w], split hi/lo
  __shared__ short XbH[32][264];
  __shared__ short XbL[32][264];
  __shared__ float Pbf[8704];  // swizzled: f(k,h,c) = k*544 + 4*(k&7) + 2*h + c

  const float4* xb4 = (const float4*)(x + ((size_t)blk << 16));
  float4 vld[8];
#pragma unroll
  for (int q = 0; q < 8; ++q) vld[q] = xb4[q * 256 + tid];  // chunk 0 prefetch

  {
    float s, c;
    sincosf((float)tid * TWOPI_256, &s, &c);
    tabc[tid] = c;
    tabs[tid] = s;
  }
  __syncthreads();  // tables ready

  // Build E (forward DFT matrix) split into hi/lo bf16: Ere=cos, Eim=-sin
  {
    const int w = tid;
#pragma unroll
    for (int kk = 0; kk < 16; ++kk) {
      const int idx = (kk * w) & 255;
      const float cv = tabc[idx];
      const float sv = -tabs[idx];
      const unsigned hc = bfp(cv);
      const unsigned hs = bfp(sv);
      const unsigned lc = bfp(cv - bf2f(hc));
      const unsigned ls = bfp(sv - bf2f(hs));
      EbRH[kk][w] = (short)hc;
      EbRL[kk][w] = (short)lc;
      EbIH[kk][w] = (short)hs;
      EbIL[kk][w] = (short)ls;
    }
  }

  // 8 chunks of 32 rows; per chunk: convert->LDS, prefetch next, MFMA (waves 0,1)
  for (int c = 0; c < 8; ++c) {
#pragma unroll
    for (int q = 0; q < 8; ++q) {
      const int row = q * 4 + wv;  // 0..31, whole wave writes one row (conflict-free)
      const float4 v = vld[q];
      const unsigned h0 = bfp(v.x), h1 = bfp(v.y), h2 = bfp(v.z), h3 = bfp(v.w);
      const unsigned l0 = bfp(v.x - bf2f(h0)), l1 = bfp(v.y - bf2f(h1));
      const unsigned l2 = bfp(v.z - bf2f(h2)), l3 = bfp(v.w - bf2f(h3));
      const int sb = (tid & 63) * 4;
      *(uint2*)&XbH[row][sb] = make_uint2(h0 | (h1 << 16), h2 | (h3 << 16));
      *(uint2*)&XbL[row][sb] = make_uint2(l0 | (l1 << 16), l2 | (l3 << 16));
    }
    __syncthreads();  // Xb (and on c==0: E) ready
    if (c < 7) {
#pragma unroll
      for (int q = 0; q < 8; ++q) vld[q] = xb4[(c + 1) * 2048 + q * 256 + tid];
    }
    if (wv < 2) {  // waves 0,1 own the chunk's two 16-row M-tiles
      f32x4 cre = {0.f, 0.f, 0.f, 0.f};
      f32x4 cim = {0.f, 0.f, 0.f, 0.f};
#pragma unroll
      for (int ks = 0; ks < 8; ++ks) {
        const int wb = ks * 32 + lhi * 8;
        const bf16x8 aH = *(const bf16x8*)&XbH[wv * 16 + llo][wb];
        const bf16x8 aL = *(const bf16x8*)&XbL[wv * 16 + llo][wb];
        const bf16x8 bRH = *(const bf16x8*)&EbRH[llo][wb];
        const bf16x8 bRL = *(const bf16x8*)&EbRL[llo][wb];
        const bf16x8 bIH = *(const bf16x8*)&EbIH[llo][wb];
        const bf16x8 bIL = *(const bf16x8*)&EbIL[llo][wb];
        cre = __builtin_amdgcn_mfma_f32_16x16x32_bf16(aH, bRH, cre, 0, 0, 0);
        cre = __builtin_amdgcn_mfma_f32_16x16x32_bf16(aL, bRH, cre, 0, 0, 0);
        cre = __builtin_amdgcn_mfma_f32_16x16x32_bf16(aH, bRL, cre, 0, 0, 0);
        cim = __builtin_amdgcn_mfma_f32_16x16x32_bf16(aH, bIH, cim, 0, 0, 0);
        cim = __builtin_amdgcn_mfma_f32_16x16x32_bf16(aL, bIH, cim, 0, 0, 0);
        cim = __builtin_amdgcn_mfma_f32_16x16x32_bf16(aH, bIL, cim, 0, 0, 0);
      }
      // D-frag: row=(lhi*4+r), col=llo  ->  Pbf swizzled layout (same as stage B expects)
#pragma unroll
      for (int r = 0; r < 4; ++r) {
        const int h = c * 32 + wv * 16 + lhi * 4 + r;
        *(float2*)&Pbf[llo * 544 + 4 * (llo & 7) + 2 * h] =
            make_float2(cre[r], cim[r]);
      }
    }
    __syncthreads();  // frag reads done before Xb overwrite next iter
  }

  // Stage B: thread = (k, tt); handles t = tt and t = tt+16 (ky = tt, 240+tt)
  const int k = tid & 15;
  const int tt = tid >> 4;  // 0..15
  const int pbase = k * 544 + 4 * (k & 7);
  float c0 = 1.f, s0 = 0.f, c1 = 1.f, s1 = 0.f;
  const float cr0 = tabc[tt], sr0 = tabs[tt];
  const float cr1 = tabc[240 + tt], sr1 = tabs[240 + tt];
  float X0r = 0.f, X0i = 0.f, X1r = 0.f, X1i = 0.f;
  for (int h = 0; h < 256; h += 2) {
    const float4 pv = *(const float4*)&Pbf[pbase + 2 * h];
    // (Pr + i Pi)(c - i s): re = Pr*c + Pi*s, im = Pi*c - Pr*s
    X0r += pv.x * c0 + pv.y * s0; X0i += pv.y * c0 - pv.x * s0;
    X1r += pv.x * c1 + pv.y * s1; X1i += pv.y * c1 - pv.x * s1;
    float cn = c0 * cr0 - s0 * sr0, sn = s0 * cr0 + c0 * sr0; c0 = cn; s0 = sn;
    cn = c1 * cr1 - s1 * sr1; sn = s1 * cr1 + c1 * sr1; c1 = cn; s1 = sn;
    X0r += pv.z * c0 + pv.w * s0; X0i += pv.w * c0 - pv.z * s0;
    X1r += pv.z * c1 + pv.w * s1; X1i += pv.w * c1 - pv.z * s1;
    cn = c0 * cr0 - s0 * sr0; sn = s0 * cr0 + c0 * sr0; c0 = cn; s0 = sn;
    cn = c1 * cr1 - s1 * sr1; sn = s1 * cr1 + c1 * sr1; c1 = cn; s1 = sn;
  }
  const int ci = blk & 63, b = blk >> 6;
  Xm[((tt * 16 + k) * 64 + ci) * 8 + b]        = make_float2(X0r, X0i);
  Xm[(((tt + 16) * 16 + k) * 64 + ci) * 8 + b] = make_float2(X1r, X1i);
}

// ---------------- Kernel 2: per (t,k): channel mixing + pair products + scaling ----
// Am layout: [b][o][t][k] float2, scaled by alpha_k = (k==0?1:2)/65536
__global__ __launch_bounds__(256) void k2_mix(const float2* __restrict__ Xm,
                                              const float* __restrict__ w1r,
                                              const float* __restrict__ w1i,
                                              const float* __restrict__ w2r,
                                              const float* __restrict__ w2i,
                                              float2* __restrict__ Am) {
  const int blk = blockIdx.x;  // t*16 + k
  const int t = blk >> 4, k = blk & 15;
  const int tp = t & 15;
  const float* __restrict__ wr = (t < 16) ? w1r : w2r;
  const float* __restrict__ wi = (t < 16) ? w1i : w2i;
  const int tid = threadIdx.x;

  __shared__ float2 Xs[64][8];  // [i][b]
  __shared__ float2 Cb[64][8];  // [o][b]

  {
    const float2* src = Xm + ((size_t)blk << 9);
    float2* dst = &Xs[0][0];
    dst[tid] = src[tid];
    dst[tid + 256] = src[tid + 256];
  }
  __syncthreads();

  // 480 mixing work-items (o in [0,60) x b in [0,8)) over 256 threads
  for (int n = tid; n < 480; n += 256) {
    const int o = n >> 3, bb = n & 7;
    const int wofs = o * 256 + tp * 16 + k;
    float ar = 0.f, ai = 0.f;
#pragma unroll 4
    for (int i = 0; i < 64; ++i) {
      const float wrv = wr[i * 15360 + wofs];  // (i*60+o)*256 + tp*16 + k
      const float wiv = wi[i * 15360 + wofs];
      const float2 xv = Xs[i][bb];
      ar += xv.x * wrv - xv.y * wiv;
      ai += xv.x * wiv + xv.y * wrv;
    }
    Cb[o][bb] = make_float2(ar, ai);
  }
  __syncthreads();
  if (tid < 32) {
    const int p = tid >> 3, bb = tid & 7;
    const float2 u = Cb[2 * p][bb], v = Cb[2 * p + 1][bb];
    Cb[60 + p][bb] = make_float2(u.x * v.x - u.y * v.y, u.x * v.y + u.y * v.x);
  }
  __syncthreads();
  const float alpha = (k == 0 ? 1.f : 2.f) * (1.f / 65536.f);
#pragma unroll
  for (int n = tid; n < 512; n += 256) {
    const int o = n >> 3, bb = n & 7;
    const float2 v = Cb[o][bb];
    Am[(((size_t)(bb * 64 + o)) * 32 + t) * 16 + k] = make_float2(v.x * alpha, v.y * alpha);
  }
}

// ---------------- Kernel 3: per (b,o): inverse H-DFT then real inverse W (MFMA) ----
// Stage D (VALU, unchanged math): Z[h][k] = sum_t Am[t][k] e^{+2pi i ky_t h/256}
//   -> Zh[h][j] bf16, j = 2k (Re) / 2k+1 (Im)
// Stage E (MFMA): out[h][w] = sum_j Z[j][h]*T[j][w], T split hi/lo bf16.
__global__ __launch_bounds__(256) void k3_inv(const float2* __restrict__ Am,
                                              float* __restrict__ out) {
  const int blk = blockIdx.x;  // b*64 + o
  const int tid = threadIdx.x;
  const int lane = tid & 63, wv = tid >> 6;
  const int llo = lane & 15, lhi = lane >> 4;

  __shared__ float tabc[256];
  __shared__ float tabs[256];
  __shared__ float2 Ams[32][16];
  __shared__ short Zh[256][40];   // A-operand [h][j], row 80B (16B aligned)
  __shared__ short TbH[256][40];  // B-operand [w][j], hi part
  __shared__ short TbL[256][40];  // lo part

  {
    float s, c;
    sincosf((float)tid * TWOPI_256, &s, &c);
    tabc[tid] = c;
    tabs[tid] = s;
  }
  {
    const float2* src = Am + ((size_t)blk << 9);
    float2* dst = &Ams[0][0];
    dst[tid] = src[tid];
    dst[tid + 256] = src[tid + 256];
  }
  __syncthreads();

  // T[2k][w] = cos(2pi k w/256); T[2k+1][w] = -sin(2pi k w/256), split hi/lo
  {
    const int w = tid;
#pragma unroll
    for (int t = 0; t < 16; ++t) {
      const int idx = (t * w) & 255;
      const float cv = tabc[idx], sv = -tabs[idx];
      const unsigned hc = bfp(cv), hs = bfp(sv);
      const unsigned lc = bfp(cv - bf2f(hc)), ls = bfp(sv - bf2f(hs));
      *(unsigned*)&TbH[w][2 * t] = hc | (hs << 16);
      *(unsigned*)&TbL[w][2 * t] = lc | (ls << 16);
    }
  }

  // Stage D: Z[h][k] = sum_t Am[t][k] * e^{+2pi i ky_t h/256}
  const int hg = tid >> 2, kg = tid & 3;
  float Zr[4][4], Zi[4][4];
#pragma unroll
  for (int i = 0; i < 4; ++i)
#pragma unroll
    for (int j = 0; j < 4; ++j) { Zr[i][j] = 0.f; Zi[i][j] = 0.f; }
  float ch[4], sh[4], crh[4], srh[4];
#pragma unroll
  for (int i = 0; i < 4; ++i) {
    const int h = hg * 4 + i;
    crh[i] = tabc[h];
    srh[i] = tabs[h];
    ch[i] = 1.f;
    sh[i] = 0.f;
  }
  for (int t = 0; t < 32; ++t) {
    if (t == 16) {
#pragma unroll
      for (int i = 0; i < 4; ++i) {
        const int idx = (240 * (hg * 4 + i)) & 255;
        ch[i] = tabc[idx];
        sh[i] = tabs[idx];
      }
    }
    const float4 a01 = *(const float4*)&Ams[t][kg * 4];
    const float4 a23 = *(const float4*)&Ams[t][kg * 4 + 2];
    const float Ar[4] = {a01.x, a01.z, a23.x, a23.z};
    const float Ai[4] = {a01.y, a01.w, a23.y, a23.w};
#pragma unroll
    for (int i = 0; i < 4; ++i) {
#pragma unroll
      for (int j = 0; j < 4; ++j) {
        Zr[i][j] += Ar[j] * ch[i] - Ai[j] * sh[i];
        Zi[i][j] += Ar[j] * sh[i] + Ai[j] * ch[i];
      }
      const float cn = ch[i] * crh[i] - sh[i] * srh[i];
      const float sn = sh[i] * crh[i] + ch[i] * srh[i];
      ch[i] = cn;
      sh[i] = sn;
    }
  }
#pragma unroll
  for (int j = 0; j < 4; ++j) {
#pragma unroll
    for (int i = 0; i < 4; ++i) {
      const int kk = kg * 4 + j, h = hg * 4 + i;
      *(unsigned*)&Zh[h][2 * kk] = bfp(Zr[i][j]) | (bfp(Zi[i][j]) << 16);
    }
  }
  __syncthreads();

  // Stage E: out[h0..][w] via mfma_f32_16x16x32_bf16 (single K-step, K=32)
  float* op = out + ((size_t)blk << 16);
#pragma unroll
  for (int hti = 0; hti < 4; ++hti) {
    const int h0 = (wv * 4 + hti) * 16;
    const bf16x8 za = *(const bf16x8*)&Zh[h0 + llo][lhi * 8];
    const int rbase = (h0 + lhi * 4) * 256 + llo;
#pragma unroll 4
    for (int wt = 0; wt < 16; ++wt) {
      const bf16x8 th = *(const bf16x8*)&TbH[wt * 16 + llo][lhi * 8];
      const bf16x8 tl = *(const bf16x8*)&TbL[wt * 16 + llo][lhi * 8];
      f32x4 acc = {0.f, 0.f, 0.f, 0.f};
      acc = __builtin_amdgcn_mfma_f32_16x16x32_bf16(za, th, acc, 0, 0, 0);
      acc = __builtin_amdgcn_mfma_f32_16x16x32_bf16(za, tl, acc, 0, 0, 0);
#pragma unroll
      for (int r = 0; r < 4; ++r) op[rbase + r * 256 + wt * 16] = acc[r];
    }
  }
}

extern "C" void kernel_launch(void* const* d_in, const int* in_sizes, int n_in,
                              void* d_out, int out_size, void* d_ws, size_t ws_size,
                              hipStream_t stream) {
  const float* x   = (const float*)d_in[0];
  const float* w1r = (const float*)d_in[1];
  const float* w1i = (const float*)d_in[2];
  const float* w2r = (const float*)d_in[3];
  const float* w2i = (const float*)d_in[4];
  float* out = (float*)d_out;

  float2* Xm = (float2*)d_ws;          // 32*16*64*8 float2 = 2 MB
  float2* Am = Xm + 262144;            // 8*64*32*16 float2 = 2 MB

  k1_fwd<<<dim3(512), dim3(256), 0, stream>>>(x, Xm);
  k2_mix<<<dim3(512), dim3(256), 0, stream>>>(Xm, w1r, w1i, w2r, w2i, Am);
  k3_inv<<<dim3(512), dim3(256), 0, stream>>>(Am, out);
}